// Round 1
// baseline (133702.332 us; speedup 1.0000x reference)
//
#include <hip/hip_runtime.h>

#define LRATE 1e-3f
static constexpr int Bn = 2048;
static constexpr int Dn = 784;
static constexpr int Hn = 256;
static constexpr int On = 10;

// ---------------------------------------------------------------------------
// Kernel 1: whitening  xw[b,d] = sum_e (x[b,e]-mean[e]) * M[d,e]
// 64x64 output tile, BK=16, 256 threads, 4x4 microtile, fp32.
// ---------------------------------------------------------------------------
__global__ __launch_bounds__(256) void whiten_kernel(
    const float* __restrict__ x, const float* __restrict__ mean,
    const float* __restrict__ Mw, float* __restrict__ xw)
{
  __shared__ __align__(16) float As[16][64];  // As[k][m]
  __shared__ __align__(16) float Bs[16][64];  // Bs[k][n]
  const int tid = threadIdx.x;
  const int b0 = blockIdx.x * 64;
  const int d0 = blockIdx.y * 64;
  const int mrow = tid >> 2;         // 0..63
  const int kq = (tid & 3) << 2;     // 0,4,8,12
  const int ty = tid >> 4, tx = tid & 15;

  float acc[4][4];
#pragma unroll
  for (int i = 0; i < 4; ++i)
#pragma unroll
    for (int j = 0; j < 4; ++j) acc[i][j] = 0.f;

  for (int k0 = 0; k0 < Dn; k0 += 16) {
    __syncthreads();
    {
      const float4 av = *(const float4*)&x[(b0 + mrow) * Dn + k0 + kq];
      const float4 mv = *(const float4*)&mean[k0 + kq];
      As[kq + 0][mrow] = av.x - mv.x;
      As[kq + 1][mrow] = av.y - mv.y;
      As[kq + 2][mrow] = av.z - mv.z;
      As[kq + 3][mrow] = av.w - mv.w;
      float4 bv = make_float4(0.f, 0.f, 0.f, 0.f);
      if (d0 + mrow < Dn) bv = *(const float4*)&Mw[(d0 + mrow) * Dn + k0 + kq];
      Bs[kq + 0][mrow] = bv.x;
      Bs[kq + 1][mrow] = bv.y;
      Bs[kq + 2][mrow] = bv.z;
      Bs[kq + 3][mrow] = bv.w;
    }
    __syncthreads();
#pragma unroll
    for (int k = 0; k < 16; ++k) {
      const float4 a = *(const float4*)&As[k][ty << 2];
      const float4 b = *(const float4*)&Bs[k][tx << 2];
      acc[0][0] += a.x * b.x; acc[0][1] += a.x * b.y; acc[0][2] += a.x * b.z; acc[0][3] += a.x * b.w;
      acc[1][0] += a.y * b.x; acc[1][1] += a.y * b.y; acc[1][2] += a.y * b.z; acc[1][3] += a.y * b.w;
      acc[2][0] += a.z * b.x; acc[2][1] += a.z * b.y; acc[2][2] += a.z * b.z; acc[2][3] += a.z * b.w;
      acc[3][0] += a.w * b.x; acc[3][1] += a.w * b.y; acc[3][2] += a.w * b.z; acc[3][3] += a.w * b.w;
    }
  }
  const int col = d0 + (tx << 2);
  if (col < Dn) {
#pragma unroll
    for (int i = 0; i < 4; ++i) {
      const int row = b0 + (ty << 2) + i;
      *(float4*)&xw[row * Dn + col] =
          make_float4(acc[i][0], acc[i][1], acc[i][2], acc[i][3]);
    }
  }
}

// ---------------------------------------------------------------------------
// Kernel 2: sequential Oja scan. ONE workgroup (1024 threads = 16 waves),
// W register-resident: lane l of wave w owns rows 4l..4l+3, cols 49w..49w+48.
// Per step: y = W x (cross-wave LDS reduce), z = W^T y (lane butterfly +
// 8-partial LDS reduce), W += lr*y*(x-z)^T.
// feats are stored in permuted order: feats[s*256 + t] = y[4*(t&63) + (t>>6)].
// ---------------------------------------------------------------------------
__global__ __launch_bounds__(1024) void oja_kernel(
    const float* __restrict__ xw, const float* __restrict__ W0,
    float* __restrict__ feats)
{
  __shared__ __align__(16) float xchunk[2][16][52];  // x row, per-wave 49-col chunks (rows 16B aligned)
  __shared__ __align__(16) float py[16][Hn];         // per-wave y partials, py[w][i*64+l]
  __shared__ __align__(16) float ybuf[Hn];           // reduced y (permuted order)
  __shared__ __align__(16) float zpart[16][8][49];   // per-wave 8 group partials of z
  __shared__ __align__(16) float uchunk[16][52];     // u = x - z, per-wave chunks

  const int tid = threadIdx.x;
  const int w = tid >> 6;
  const int l = tid & 63;
  const int row0 = l << 2;     // first of this lane's 4 rows
  const int c0 = 49 * w;       // first of this wave's 49 cols
  const int w2 = tid / 49;     // reduce-phase mapping (valid for tid<784)
  const int k2 = tid - w2 * 49;

  float Wreg[4][49];
#pragma unroll
  for (int i = 0; i < 4; ++i)
#pragma unroll
    for (int k = 0; k < 49; ++k)
      Wreg[i][k] = W0[(row0 + i) * Dn + c0 + k];

  if (tid < Dn) xchunk[0][w2][k2] = xw[tid];
  __syncthreads();

  for (int s = 0; s < Bn; ++s) {
    const int cur = s & 1, nxt = cur ^ 1;

    // prefetch next x row into a register (written to LDS mid-step)
    float xnext = 0.f;
    if (tid < Dn && s + 1 < Bn) xnext = xw[(s + 1) * Dn + tid];

    // ---- op1: y = W x ----
    float yp0 = 0.f, yp1 = 0.f, yp2 = 0.f, yp3 = 0.f;
    {
      const float4* xc = (const float4*)&xchunk[cur][w][0];
#pragma unroll
      for (int k4 = 0; k4 < 12; ++k4) {
        const float4 xv = xc[k4];
        const int k = k4 << 2;
        yp0 += Wreg[0][k] * xv.x + Wreg[0][k + 1] * xv.y + Wreg[0][k + 2] * xv.z + Wreg[0][k + 3] * xv.w;
        yp1 += Wreg[1][k] * xv.x + Wreg[1][k + 1] * xv.y + Wreg[1][k + 2] * xv.z + Wreg[1][k + 3] * xv.w;
        yp2 += Wreg[2][k] * xv.x + Wreg[2][k + 1] * xv.y + Wreg[2][k + 2] * xv.z + Wreg[2][k + 3] * xv.w;
        yp3 += Wreg[3][k] * xv.x + Wreg[3][k + 1] * xv.y + Wreg[3][k + 2] * xv.z + Wreg[3][k + 3] * xv.w;
      }
      const float xv = xchunk[cur][w][48];
      yp0 += Wreg[0][48] * xv; yp1 += Wreg[1][48] * xv;
      yp2 += Wreg[2][48] * xv; yp3 += Wreg[3][48] * xv;
    }
    // conflict-free transposed partial write: py[w][i*64 + l]
    py[w][l] = yp0;
    py[w][64 + l] = yp1;
    py[w][128 + l] = yp2;
    py[w][192 + l] = yp3;
    __syncthreads();
    if (tid < Hn) {
      float a = 0.f;
#pragma unroll
      for (int q = 0; q < 16; ++q) a += py[q][tid];
      ybuf[tid] = a;
      feats[s * Hn + tid] = a;  // permuted order; readout kernel compensates
    }
    __syncthreads();
    // lane l needs rows 4l..4l+3  ->  ybuf[i*64 + l]
    const float y0 = ybuf[l], y1 = ybuf[64 + l], y2 = ybuf[128 + l], y3 = ybuf[192 + l];

    // ---- op2: z = W^T y ----
    float zp[49];
#pragma unroll
    for (int k = 0; k < 49; ++k)
      zp[k] = Wreg[0][k] * y0 + Wreg[1][k] * y1 + Wreg[2][k] * y2 + Wreg[3][k] * y3;
#pragma unroll
    for (int k = 0; k < 49; ++k) {
      zp[k] += __shfl_xor(zp[k], 1);
      zp[k] += __shfl_xor(zp[k], 2);
      zp[k] += __shfl_xor(zp[k], 4);
    }
    if ((l & 7) == 0) {
      const int g = l >> 3;
#pragma unroll
      for (int k = 0; k < 49; ++k) zpart[w][g][k] = zp[k];
    }
    __syncthreads();
    if (tid < Dn) {
      float a = 0.f;
#pragma unroll
      for (int g = 0; g < 8; ++g) a += zpart[w2][g][k2];
      uchunk[w2][k2] = xchunk[cur][w2][k2] - a;
      if (s + 1 < Bn) xchunk[nxt][w2][k2] = xnext;
    }
    __syncthreads();

    // ---- op3: W += lr * y * u^T ----
    const float ly0 = LRATE * y0, ly1 = LRATE * y1, ly2 = LRATE * y2, ly3 = LRATE * y3;
    {
      const float4* uc = (const float4*)&uchunk[w][0];
#pragma unroll
      for (int k4 = 0; k4 < 12; ++k4) {
        const float4 uv = uc[k4];
        const int k = k4 << 2;
        Wreg[0][k] += ly0 * uv.x; Wreg[0][k + 1] += ly0 * uv.y; Wreg[0][k + 2] += ly0 * uv.z; Wreg[0][k + 3] += ly0 * uv.w;
        Wreg[1][k] += ly1 * uv.x; Wreg[1][k + 1] += ly1 * uv.y; Wreg[1][k + 2] += ly1 * uv.z; Wreg[1][k + 3] += ly1 * uv.w;
        Wreg[2][k] += ly2 * uv.x; Wreg[2][k + 1] += ly2 * uv.y; Wreg[2][k + 2] += ly2 * uv.z; Wreg[2][k + 3] += ly2 * uv.w;
        Wreg[3][k] += ly3 * uv.x; Wreg[3][k + 1] += ly3 * uv.y; Wreg[3][k + 2] += ly3 * uv.z; Wreg[3][k + 3] += ly3 * uv.w;
      }
      const float uv = uchunk[w][48];
      Wreg[0][48] += ly0 * uv; Wreg[1][48] += ly1 * uv;
      Wreg[2][48] += ly2 * uv; Wreg[3][48] += ly3 * uv;
    }
    // no barrier needed here: next step's first LDS writes (py) are only
    // consumed after the following barrier, and all buffers written next step
    // are separated from this step's reads by >=1 barrier.
  }
}

// ---------------------------------------------------------------------------
// Kernel 3: logits[b,o] = sum_h relu(feats_perm[b,t]) * R[o, r(t)] + bias[o]
// where r(t) = 4*(t&63) + (t>>6) undoes the oja kernel's permuted feat order.
// ---------------------------------------------------------------------------
__global__ __launch_bounds__(256) void readout_kernel(
    const float* __restrict__ feats, const float* __restrict__ R,
    const float* __restrict__ bias, float* __restrict__ out)
{
  const int g = blockIdx.x * 256 + threadIdx.x;
  if (g >= Bn * On) return;
  const int b = g / On;
  const int o = g - b * On;
  const float* f = feats + b * Hn;
  const float* r = R + o * Hn;
  float acc = bias[o];
#pragma unroll 4
  for (int t = 0; t < Hn; ++t) {
    const int rh = ((t & 63) << 2) | (t >> 6);
    acc += fmaxf(f[t], 0.f) * r[rh];
  }
  out[g] = acc;
}

// ---------------------------------------------------------------------------
extern "C" void kernel_launch(void* const* d_in, const int* in_sizes, int n_in,
                              void* d_out, int out_size, void* d_ws, size_t ws_size,
                              hipStream_t stream) {
  const float* x    = (const float*)d_in[0];  // [2048,784]
  const float* mean = (const float*)d_in[1];  // [784]
  const float* Mw   = (const float*)d_in[2];  // [784,784]
  const float* W0   = (const float*)d_in[3];  // [256,784]
  const float* R    = (const float*)d_in[4];  // [10,256]
  const float* bias = (const float*)d_in[5];  // [10]
  float* out = (float*)d_out;                 // [2048,10]

  float* xw    = (float*)d_ws;                // [2048,784]
  float* feats = xw + (size_t)Bn * Dn;        // [2048,256] (permuted h order)

  whiten_kernel<<<dim3(Bn / 64, (Dn + 63) / 64), 256, 0, stream>>>(x, mean, Mw, xw);
  oja_kernel<<<1, 1024, 0, stream>>>(xw, W0, feats);
  readout_kernel<<<(Bn * On + 255) / 256, 256, 0, stream>>>(feats, R, bias, out);
}

// Round 2
// 6153.575 us; speedup vs baseline: 21.7276x; 21.7276x over previous
//
#include <hip/hip_runtime.h>

#define LRATE 1e-3f
static constexpr int Bn = 2048;
static constexpr int Dn = 784;
static constexpr int Hn = 256;
static constexpr int On = 10;
static constexpr int Cc = 64;           // chunk size
static constexpr int NCHUNK = Bn / Cc;  // 32

// LDS row strides (floats): multiples of 4 for aligned float4 (ds_read_b128)
static constexpr int AS = 68;   // 64x64 matrices
static constexpr int YS = 260;  // 64x256 matrices

// ---------------------------------------------------------------------------
// Kernel 1: whitening  xw[b,d] = sum_e (x[b,e]-mean[e]) * M[d,e]
// ---------------------------------------------------------------------------
__global__ __launch_bounds__(256) void whiten_kernel(
    const float* __restrict__ x, const float* __restrict__ mean,
    const float* __restrict__ Mw, float* __restrict__ xw)
{
  __shared__ __align__(16) float As[16][64];
  __shared__ __align__(16) float Bs[16][64];
  const int tid = threadIdx.x;
  const int b0 = blockIdx.x * 64;
  const int d0 = blockIdx.y * 64;
  const int mrow = tid >> 2;
  const int kq = (tid & 3) << 2;
  const int ty = tid >> 4, tx = tid & 15;

  float acc[4][4];
#pragma unroll
  for (int i = 0; i < 4; ++i)
#pragma unroll
    for (int j = 0; j < 4; ++j) acc[i][j] = 0.f;

  for (int k0 = 0; k0 < Dn; k0 += 16) {
    __syncthreads();
    {
      const float4 av = *(const float4*)&x[(b0 + mrow) * Dn + k0 + kq];
      const float4 mv = *(const float4*)&mean[k0 + kq];
      As[kq + 0][mrow] = av.x - mv.x;
      As[kq + 1][mrow] = av.y - mv.y;
      As[kq + 2][mrow] = av.z - mv.z;
      As[kq + 3][mrow] = av.w - mv.w;
      float4 bv = make_float4(0.f, 0.f, 0.f, 0.f);
      if (d0 + mrow < Dn) bv = *(const float4*)&Mw[(d0 + mrow) * Dn + k0 + kq];
      Bs[kq + 0][mrow] = bv.x;
      Bs[kq + 1][mrow] = bv.y;
      Bs[kq + 2][mrow] = bv.z;
      Bs[kq + 3][mrow] = bv.w;
    }
    __syncthreads();
#pragma unroll
    for (int k = 0; k < 16; ++k) {
      const float4 a = *(const float4*)&As[k][ty << 2];
      const float4 b = *(const float4*)&Bs[k][tx << 2];
      acc[0][0] += a.x * b.x; acc[0][1] += a.x * b.y; acc[0][2] += a.x * b.z; acc[0][3] += a.x * b.w;
      acc[1][0] += a.y * b.x; acc[1][1] += a.y * b.y; acc[1][2] += a.y * b.z; acc[1][3] += a.y * b.w;
      acc[2][0] += a.z * b.x; acc[2][1] += a.z * b.y; acc[2][2] += a.z * b.z; acc[2][3] += a.z * b.w;
      acc[3][0] += a.w * b.x; acc[3][1] += a.w * b.y; acc[3][2] += a.w * b.z; acc[3][3] += a.w * b.w;
    }
  }
  const int col = d0 + (tx << 2);
  if (col < Dn) {
#pragma unroll
    for (int i = 0; i < 4; ++i) {
      const int row = b0 + (ty << 2) + i;
      *(float4*)&xw[row * Dn + col] =
          make_float4(acc[i][0], acc[i][1], acc[i][2], acc[i][3]);
    }
  }
}

// ---------------------------------------------------------------------------
// Kernel 2: per-chunk Gram blocks  S_c = X_c X_c^T   (all chunks, parallel)
// ---------------------------------------------------------------------------
__global__ __launch_bounds__(256) void sgram_kernel(
    const float* __restrict__ xw, float* __restrict__ S_all)
{
  __shared__ __align__(16) float Xs[64 * 396];  // 64 x 392 staged (stride 396)
  const int t = threadIdx.x;
  const int c = blockIdx.x;
  const float* xc = xw + (size_t)c * Cc * Dn;
  const int ti = t >> 4, tj = t & 15;
  float acc[4][4];
#pragma unroll
  for (int a = 0; a < 4; ++a)
#pragma unroll
    for (int b = 0; b < 4; ++b) acc[a][b] = 0.f;

  for (int pass = 0; pass < 2; ++pass) {
    __syncthreads();
    for (int e4 = t; e4 < 64 * 98; e4 += 256) {
      const int r = e4 / 98, c4 = e4 - r * 98;
      *(float4*)&Xs[r * 396 + 4 * c4] =
          *(const float4*)&xc[r * Dn + pass * 392 + 4 * c4];
    }
    __syncthreads();
    for (int k4 = 0; k4 < 98; ++k4) {
      float4 A[4], Bv[4];
#pragma unroll
      for (int a = 0; a < 4; ++a) A[a] = *(const float4*)&Xs[(4 * ti + a) * 396 + 4 * k4];
#pragma unroll
      for (int b = 0; b < 4; ++b) Bv[b] = *(const float4*)&Xs[(4 * tj + b) * 396 + 4 * k4];
#pragma unroll
      for (int a = 0; a < 4; ++a)
#pragma unroll
        for (int b = 0; b < 4; ++b)
          acc[a][b] += A[a].x * Bv[b].x + A[a].y * Bv[b].y + A[a].z * Bv[b].z + A[a].w * Bv[b].w;
    }
  }
  float* Sc = S_all + (size_t)c * Cc * Cc;
#pragma unroll
  for (int a = 0; a < 4; ++a)
#pragma unroll
    for (int b = 0; b < 4; ++b)
      Sc[(4 * ti + a) * Cc + 4 * tj + b] = acc[a][b];
}

// ---------------------------------------------------------------------------
// Kernel 3 (per chunk): yhat[r][h] = sum_d X_c[r][d] * W[h][d]   [64 x 256]
// grid 64 WGs x 256 thr; WG w owns 4 h's.
// ---------------------------------------------------------------------------
__global__ __launch_bounds__(256) void yhat_kernel(
    const float* __restrict__ xc, const float* __restrict__ W,
    float* __restrict__ yhat)
{
  const int t = threadIdx.x;
  const int r = t & 63, hh = t >> 6;
  const int h = blockIdx.x * 4 + hh;
  const float4* xr = (const float4*)&xc[r * Dn];
  const float4* wr = (const float4*)&W[h * Dn];
  float acc = 0.f;
#pragma unroll 4
  for (int f = 0; f < 196; ++f) {
    const float4 a = xr[f], b = wr[f];
    acc += a.x * b.x + a.y * b.y + a.z * b.z + a.w * b.w;
  }
  yhat[r * Hn + h] = acc;
}

// ---------------------------------------------------------------------------
// Kernel 4 (per chunk): the small sequential recurrence. ONE WG, 256 threads.
// In LDS: yh[64][256], T, S, alpha, beta, q (all 64x64, stride 68).
// alpha/beta are unit-lower-triangular (zero-padded => full-width sums exact).
// Outputs: feats rows (Y = alpha*yhat) and beta (to global, for upd_kernel).
// ---------------------------------------------------------------------------
__global__ __launch_bounds__(256, 1) void seq_kernel(
    const float* __restrict__ yhat_g, const float* __restrict__ S_g,
    float* __restrict__ feats_c, float* __restrict__ beta_g)
{
  __shared__ __align__(16) float yh[64 * YS];
  __shared__ __align__(16) float Ts[64 * AS];
  __shared__ __align__(16) float Ss[64 * AS];
  __shared__ __align__(16) float al[64 * AS];
  __shared__ __align__(16) float be[64 * AS];
  __shared__ __align__(16) float qs[64 * AS];
  __shared__ __align__(16) float hbuf[AS];
  __shared__ __align__(16) float pbuf[AS];

  const int t = threadIdx.x;
  const int k = t >> 2;       // 0..63 (row / output index per 4-lane group)
  const int qr = t & 3;       // quarter within the 4-lane group (same wave)
  const int m0 = qr * 16;

  // ---- prologue: zero + load ----
  for (int e = t; e < 64 * AS; e += 256) { al[e] = 0.f; be[e] = 0.f; qs[e] = 0.f; }
  for (int e = t; e < Cc * Cc; e += 256)
    Ss[(e >> 6) * AS + (e & 63)] = S_g[e];
  for (int e4 = t; e4 < 64 * 64; e4 += 256) {  // 64*256 floats = 4096 float4
    const int r = e4 >> 6, c4 = e4 & 63;
    *(float4*)&yh[r * YS + 4 * c4] = ((const float4*)yhat_g)[e4];
  }
  __syncthreads();
  if (t < 64) { al[t * AS + t] = 1.f; be[t * AS + t] = 1.f; }
  // T = yh * yh^T  (16x16 thread grid, 4x4 blocks)
  {
    const int ti = t >> 4, tj = t & 15;
    float acc[4][4];
#pragma unroll
    for (int a = 0; a < 4; ++a)
#pragma unroll
      for (int b = 0; b < 4; ++b) acc[a][b] = 0.f;
    for (int k4 = 0; k4 < 64; ++k4) {
      float4 A[4], Bv[4];
#pragma unroll
      for (int a = 0; a < 4; ++a) A[a] = *(const float4*)&yh[(4 * ti + a) * YS + 4 * k4];
#pragma unroll
      for (int b = 0; b < 4; ++b) Bv[b] = *(const float4*)&yh[(4 * tj + b) * YS + 4 * k4];
#pragma unroll
      for (int a = 0; a < 4; ++a)
#pragma unroll
        for (int b = 0; b < 4; ++b)
          acc[a][b] += A[a].x * Bv[b].x + A[a].y * Bv[b].y + A[a].z * Bv[b].z + A[a].w * Bv[b].w;
    }
#pragma unroll
    for (int a = 0; a < 4; ++a)
#pragma unroll
      for (int b = 0; b < 4; ++b)
        Ts[(4 * ti + a) * AS + 4 * tj + b] = acc[a][b];
  }
  __syncthreads();

  // ---- the 64 sequential steps ----
  for (int i = 0; i < Cc; ++i) {
    // P1: h[k] = sum_m al[k][m] * T[i][m]      (T symmetric: row read)
    {
      float acc = 0.f;
      const float4* arow = (const float4*)&al[k * AS + m0];
      const float4* trow = (const float4*)&Ts[i * AS + m0];
#pragma unroll
      for (int f = 0; f < 4; ++f) {
        const float4 a = arow[f], b = trow[f];
        acc += a.x * b.x + a.y * b.y + a.z * b.z + a.w * b.w;
      }
      acc += __shfl_xor(acc, 1);
      acc += __shfl_xor(acc, 2);
      if (qr == 0) hbuf[k] = acc;
    }
    __syncthreads();
    // P2: p[j] = sum_k be[j][k] * (S[i][k] - h[k])   (j := k-index of thread)
    {
      float acc = 0.f;
      const float4* brow = (const float4*)&be[k * AS + m0];
      const float4* srow = (const float4*)&Ss[i * AS + m0];
      const float4* hrow = (const float4*)&hbuf[m0];
#pragma unroll
      for (int f = 0; f < 4; ++f) {
        const float4 b = brow[f], s = srow[f], hv = hrow[f];
        acc += b.x * (s.x - hv.x) + b.y * (s.y - hv.y) + b.z * (s.z - hv.z) + b.w * (s.w - hv.w);
      }
      acc += __shfl_xor(acc, 1);
      acc += __shfl_xor(acc, 2);
      if (qr == 0) pbuf[k] = acc;
    }
    __syncthreads();
    // P3a: alpha[i][m] = LR * sum_j p[j] * al[j][m]   (m := k)
    {
      float acc = 0.f;
#pragma unroll
      for (int s_ = 0; s_ < 16; ++s_) {
        const int j = m0 + s_;
        acc += pbuf[j] * al[j * AS + k];
      }
      acc += __shfl_xor(acc, 1);
      acc += __shfl_xor(acc, 2);
      if (qr == 0 && k < i) al[i * AS + k] = LRATE * acc;
    }
    // P3b: q[k][i] = h[k] + LR * sum_j p[j] * q[k][j]
    {
      float acc = 0.f;
      const float4* qrow = (const float4*)&qs[k * AS + m0];
      const float4* prow = (const float4*)&pbuf[m0];
#pragma unroll
      for (int f = 0; f < 4; ++f) {
        const float4 qv = qrow[f], pv = prow[f];
        acc += qv.x * pv.x + qv.y * pv.y + qv.z * pv.z + qv.w * pv.w;
      }
      acc += __shfl_xor(acc, 1);
      acc += __shfl_xor(acc, 2);
      if (qr == 0 && k < i) {
        const float v = hbuf[k] + LRATE * acc;
        qs[k * AS + i] = v;
        qs[i * AS + k] = v;
      }
    }
    __syncthreads();
    // P4a: beta[i][m] = -LR * sum_j q[i][j] * be[j][m]   (m := k)
    {
      float acc = 0.f;
#pragma unroll
      for (int s_ = 0; s_ < 16; ++s_) {
        const int j = m0 + s_;
        acc += qs[i * AS + j] * be[j * AS + k];
      }
      acc += __shfl_xor(acc, 1);
      acc += __shfl_xor(acc, 2);
      if (qr == 0 && k < i) be[i * AS + k] = -LRATE * acc;
    }
    // P4b: q[i][i] = T[i][i] + LR * sum_{j<i} p[j]*(h[j] + q[i][j])   (wave 0)
    if (t < 64) {
      float v = (t < i) ? pbuf[t] * (hbuf[t] + qs[i * AS + t]) : 0.f;
      v += __shfl_xor(v, 1);  v += __shfl_xor(v, 2);  v += __shfl_xor(v, 4);
      v += __shfl_xor(v, 8);  v += __shfl_xor(v, 16); v += __shfl_xor(v, 32);
      if (t == 0) qs[i * AS + i] = Ts[i * AS + i] + LRATE * v;
    }
    __syncthreads();
  }

  // ---- epilogue: beta -> global; Y = alpha * yhat -> feats ----
  for (int e4 = t; e4 < 1024; e4 += 256) {  // 64*64 floats
    const int r = e4 >> 4, c4 = e4 & 15;
    ((float4*)beta_g)[e4] = *(const float4*)&be[r * AS + 4 * c4];
  }
  {
    const int r = k;  // t>>2
    float4 a4[16];
#pragma unroll
    for (int f = 0; f < 16; ++f) a4[f] = *(const float4*)&al[r * AS + 4 * f];
    float4 acc[16];
#pragma unroll
    for (int f = 0; f < 16; ++f) acc[f] = make_float4(0.f, 0.f, 0.f, 0.f);
#pragma unroll
    for (int m4 = 0; m4 < 16; ++m4) {
      const float4 av = a4[m4];
      const float4* y0 = (const float4*)&yh[(4 * m4 + 0) * YS + m0 * 4];
      const float4* y1 = (const float4*)&yh[(4 * m4 + 1) * YS + m0 * 4];
      const float4* y2 = (const float4*)&yh[(4 * m4 + 2) * YS + m0 * 4];
      const float4* y3 = (const float4*)&yh[(4 * m4 + 3) * YS + m0 * 4];
#pragma unroll
      for (int f = 0; f < 16; ++f) {
        const float4 v0 = y0[f], v1 = y1[f], v2 = y2[f], v3 = y3[f];
        acc[f].x += av.x * v0.x + av.y * v1.x + av.z * v2.x + av.w * v3.x;
        acc[f].y += av.x * v0.y + av.y * v1.y + av.z * v2.y + av.w * v3.y;
        acc[f].z += av.x * v0.z + av.y * v1.z + av.z * v2.z + av.w * v3.z;
        acc[f].w += av.x * v0.w + av.y * v1.w + av.z * v2.w + av.w * v3.w;
      }
    }
    float4* dst = (float4*)&feats_c[r * Hn + m0 * 4];  // h-range [qr*64, qr*64+64)
#pragma unroll
    for (int f = 0; f < 16; ++f) dst[f] = acc[f];
  }
}

// ---------------------------------------------------------------------------
// Kernel 5 (per chunk): V = X_c - Y W ; U = beta V ; W += LR * Y^T U.
// grid 98 WGs, each owns 8 consecutive W columns.
// ---------------------------------------------------------------------------
__global__ __launch_bounds__(256, 1) void upd_kernel(
    const float* __restrict__ xc, const float* __restrict__ Yg,
    const float* __restrict__ beta_g, float* __restrict__ W)
{
  __shared__ __align__(16) float Yl[64 * YS];
  __shared__ __align__(16) float bl[64 * AS];
  __shared__ __align__(16) float WlT[8 * YS];
  __shared__ __align__(16) float XT[8 * 64];
  __shared__ __align__(16) float VT[8 * 64];
  __shared__ __align__(16) float UT[8 * 64];
  const int t = threadIdx.x;
  const int d0 = blockIdx.x * 8;

  {  // load Y
    const int r = t >> 2, qr = t & 3;
    const float4* src = (const float4*)&Yg[r * Hn + qr * 64];
    float4* dst = (float4*)&Yl[r * YS + qr * 64];
#pragma unroll
    for (int f = 0; f < 16; ++f) dst[f] = src[f];
  }
#pragma unroll
  for (int f = 0; f < 4; ++f) {  // load beta
    const int e4 = t + 256 * f;
    const int r = e4 >> 4, c4 = e4 & 15;
    *(float4*)&bl[r * AS + 4 * c4] = ((const float4*)beta_g)[e4];
  }
  {  // load W slice (transposed)
    const float4* wsrc = (const float4*)&W[t * Dn + d0];
    const float4 w0 = wsrc[0], w1 = wsrc[1];
    WlT[0 * YS + t] = w0.x; WlT[1 * YS + t] = w0.y; WlT[2 * YS + t] = w0.z; WlT[3 * YS + t] = w0.w;
    WlT[4 * YS + t] = w1.x; WlT[5 * YS + t] = w1.y; WlT[6 * YS + t] = w1.z; WlT[7 * YS + t] = w1.w;
  }
  if (t < 64) {  // load X slice (transposed)
    const float4* xsrc = (const float4*)&xc[t * Dn + d0];
    const float4 x0 = xsrc[0], x1 = xsrc[1];
    XT[0 * 64 + t] = x0.x; XT[1 * 64 + t] = x0.y; XT[2 * 64 + t] = x0.z; XT[3 * 64 + t] = x0.w;
    XT[4 * 64 + t] = x1.x; XT[5 * 64 + t] = x1.y; XT[6 * 64 + t] = x1.z; XT[7 * 64 + t] = x1.w;
  }
  __syncthreads();
  const int r = t & 63, da = t >> 6, db = da + 4;
  {  // V = X - Y W
    float va = XT[da * 64 + r], vb = XT[db * 64 + r];
    const float4* yrow = (const float4*)&Yl[r * YS];
    const float4* wa = (const float4*)&WlT[da * YS];
    const float4* wb = (const float4*)&WlT[db * YS];
#pragma unroll 8
    for (int f = 0; f < 64; ++f) {
      const float4 y = yrow[f], A = wa[f], Bv = wb[f];
      va -= y.x * A.x + y.y * A.y + y.z * A.z + y.w * A.w;
      vb -= y.x * Bv.x + y.y * Bv.y + y.z * Bv.z + y.w * Bv.w;
    }
    VT[da * 64 + r] = va; VT[db * 64 + r] = vb;
  }
  __syncthreads();
  {  // U = beta V
    float ua = 0.f, ub = 0.f;
    const float4* br = (const float4*)&bl[r * AS];
    const float4* vta = (const float4*)&VT[da * 64];
    const float4* vtb = (const float4*)&VT[db * 64];
#pragma unroll
    for (int f = 0; f < 16; ++f) {
      const float4 b = br[f], A = vta[f], Bv = vtb[f];
      ua += b.x * A.x + b.y * A.y + b.z * A.z + b.w * A.w;
      ub += b.x * Bv.x + b.y * Bv.y + b.z * Bv.z + b.w * Bv.w;
    }
    UT[da * 64 + r] = ua; UT[db * 64 + r] = ub;
  }
  __syncthreads();
  {  // W[h=t][d0+dj] += LR * sum_r Y[r][h] * U[r][dj]
    float wacc[8];
#pragma unroll
    for (int dj = 0; dj < 8; ++dj) wacc[dj] = 0.f;
    for (int r4 = 0; r4 < 16; ++r4) {
      float4 u[8];
#pragma unroll
      for (int dj = 0; dj < 8; ++dj) u[dj] = *(const float4*)&UT[dj * 64 + 4 * r4];
      const float y0 = Yl[(4 * r4 + 0) * YS + t];
      const float y1 = Yl[(4 * r4 + 1) * YS + t];
      const float y2 = Yl[(4 * r4 + 2) * YS + t];
      const float y3 = Yl[(4 * r4 + 3) * YS + t];
#pragma unroll
      for (int dj = 0; dj < 8; ++dj)
        wacc[dj] += y0 * u[dj].x + y1 * u[dj].y + y2 * u[dj].z + y3 * u[dj].w;
    }
    float4 o0, o1;
    o0.x = WlT[0 * YS + t] + LRATE * wacc[0];
    o0.y = WlT[1 * YS + t] + LRATE * wacc[1];
    o0.z = WlT[2 * YS + t] + LRATE * wacc[2];
    o0.w = WlT[3 * YS + t] + LRATE * wacc[3];
    o1.x = WlT[4 * YS + t] + LRATE * wacc[4];
    o1.y = WlT[5 * YS + t] + LRATE * wacc[5];
    o1.z = WlT[6 * YS + t] + LRATE * wacc[6];
    o1.w = WlT[7 * YS + t] + LRATE * wacc[7];
    float4* wdst = (float4*)&W[t * Dn + d0];
    wdst[0] = o0; wdst[1] = o1;
  }
}

// ---------------------------------------------------------------------------
// Kernel 6: logits = relu(feats) @ R^T + bias
// ---------------------------------------------------------------------------
__global__ __launch_bounds__(256) void readout_kernel(
    const float* __restrict__ feats, const float* __restrict__ R,
    const float* __restrict__ bias, float* __restrict__ out)
{
  const int g = blockIdx.x * 256 + threadIdx.x;
  if (g >= Bn * On) return;
  const int b = g / On;
  const int o = g - b * On;
  const float* f = feats + b * Hn;
  const float* r = R + o * Hn;
  float acc = bias[o];
#pragma unroll 8
  for (int h = 0; h < Hn; ++h) acc += fmaxf(f[h], 0.f) * r[h];
  out[g] = acc;
}

// ---------------------------------------------------------------------------
extern "C" void kernel_launch(void* const* d_in, const int* in_sizes, int n_in,
                              void* d_out, int out_size, void* d_ws, size_t ws_size,
                              hipStream_t stream) {
  const float* x    = (const float*)d_in[0];  // [2048,784]
  const float* mean = (const float*)d_in[1];  // [784]
  const float* Mw   = (const float*)d_in[2];  // [784,784]
  const float* W0   = (const float*)d_in[3];  // [256,784]
  const float* R    = (const float*)d_in[4];  // [10,256]
  const float* bias = (const float*)d_in[5];  // [10]
  float* out = (float*)d_out;                 // [2048,10]

  float* p = (float*)d_ws;
  float* xw     = p;  p += (size_t)Bn * Dn;        // 1,605,632
  float* feats  = p;  p += (size_t)Bn * Hn;        //   524,288
  float* W_dyn  = p;  p += (size_t)Hn * Dn;        //   200,704
  float* S_all  = p;  p += (size_t)NCHUNK * Cc * Cc; // 131,072
  float* yhat   = p;  p += (size_t)Cc * Hn;        //    16,384
  float* beta_g = p;  p += (size_t)Cc * Cc;        //     4,096
  (void)ws_size; (void)n_in; (void)in_sizes; (void)out_size;

  whiten_kernel<<<dim3(Bn / 64, (Dn + 63) / 64), 256, 0, stream>>>(x, mean, Mw, xw);
  sgram_kernel<<<NCHUNK, 256, 0, stream>>>(xw, S_all);
  hipMemcpyAsync(W_dyn, W0, (size_t)Hn * Dn * sizeof(float),
                 hipMemcpyDeviceToDevice, stream);

  for (int c = 0; c < NCHUNK; ++c) {
    const float* xc = xw + (size_t)c * Cc * Dn;
    float* feats_c  = feats + (size_t)c * Cc * Hn;
    yhat_kernel<<<64, 256, 0, stream>>>(xc, W_dyn, yhat);
    seq_kernel<<<1, 256, 0, stream>>>(yhat, S_all + (size_t)c * Cc * Cc,
                                      feats_c, beta_g);
    upd_kernel<<<98, 256, 0, stream>>>(xc, feats_c, beta_g, W_dyn);
  }

  readout_kernel<<<(Bn * On + 255) / 256, 256, 0, stream>>>(feats, R, bias, out);
}